// Round 5
// baseline (4422.256 us; speedup 1.0000x reference)
//
#include <hip/hip_runtime.h>
#include <hip/hip_bf16.h>
#include <cstdint>
#include <cstddef>

#define BB 256
#define TT 20
#define NOBJ 36
#define OBJD 2048
#define ATTD 1024
#define DECD 1024
#define VOCAB 10000
#define NBIG  17168   // 7168 (Wda|Wfb|Whh) + 10000 (Wfc)
#define NBIGP 17280   // padded to multiple of 128 (135 tiles)
#define NSPLIT 7168
#define NGRID 256     // persistent blocks (1 per CU)

typedef unsigned short u16;
typedef __attribute__((ext_vector_type(8))) short short8v;
typedef __attribute__((ext_vector_type(4))) float float4v;

__device__ inline u16 f2bf(float f) {
    __hip_bfloat16 h = __float2bfloat16(f);
    return *reinterpret_cast<u16*>(&h);
}
__device__ inline float bu(u16 u) {
    union { unsigned int i; float f; } x;
    x.i = ((unsigned int)u) << 16;
    return x.f;
}
__device__ inline float sigf(float x) { return 1.f / (1.f + expf(-x)); }

// async global->LDS, 16B per lane. LDS dest must be wave-uniform base.
__device__ inline void gload16(const u16* g, u16* l) {
    __builtin_amdgcn_global_load_lds(
        (const __attribute__((address_space(1))) unsigned int*)g,
        (__attribute__((address_space(3))) unsigned int*)l, 16, 0, 0);
}

struct MegaParams {
    const float* enc; const float* objs; const int* caps; const int* clen;
    const float* emb;
    const float* Wea; const float* bea; const float* Wda; const float* bda;
    const float* wfa; const float* bfa; const float* Wfb; const float* bfb;
    const float* Wih; const float* Whh; const float* bih; const float* bhh;
    const float* Wfc; const float* bfc;
    float* outP; float* out_caps; float* out_len; float* out_alph; float* out_sind;
    int* bar; int* sidx; int* slen; int* cnt;
    u16* objsb; u16* Wbigb; float* bcat; u16* Wihb; float* bsum; u16* Weab;
    u16* att1b; u16* Xb; u16* Gxb; float* Hcat; u16* aweb; float* G2p;
    float* h; float* c; u16* hb;
};

// ---------------------------------------------------------------------------
// Device-scope grid barrier (blocks are co-resident: grid == 256 == #CUs,
// LDS 52KB and VGPR budget leave >=2 block slots per CU -> no deadlock).
// ---------------------------------------------------------------------------
__device__ inline void grid_bar(int* bar) {
    __syncthreads();
    if (threadIdx.x == 0) {
        __threadfence();
        const int gen = __hip_atomic_load(&bar[1], __ATOMIC_RELAXED, __HIP_MEMORY_SCOPE_AGENT);
        const int prev = __hip_atomic_fetch_add(&bar[0], 1, __ATOMIC_ACQ_REL, __HIP_MEMORY_SCOPE_AGENT);
        if (prev == NGRID - 1) {
            __hip_atomic_store(&bar[0], 0, __ATOMIC_RELAXED, __HIP_MEMORY_SCOPE_AGENT);
            __hip_atomic_store(&bar[1], gen + 1, __ATOMIC_RELEASE, __HIP_MEMORY_SCOPE_AGENT);
        } else {
            while (__hip_atomic_load(&bar[1], __ATOMIC_RELAXED, __HIP_MEMORY_SCOPE_AGENT) == gen) {
                __builtin_amdgcn_s_sleep(1);
            }
        }
        __threadfence();
    }
    __syncthreads();
}

// ---------------------------------------------------------------------------
// One 128x128 GEMM tile job: C[m,n] = sum_k A[m0+m,k]*B[n0+n,k] + bias[n].
// 3-stage pipelined (counted vmcnt, never 0 mid-loop), global_load_lds with
// source pre-swizzle (LDS linear), swizzled ds_read_b128. K % 32 == 0, K>=96.
// n < nsplit -> Cf (f32) or Cb (bf16); else C2 f32, rows m >= act skipped
// (output pre-zeroed).
// ---------------------------------------------------------------------------
__device__ void gemm_job(
    u16* AsB, u16* BsB,                       // 3*4096 u16 each
    const u16* __restrict__ A, int lda,
    const u16* __restrict__ B, int ldb,
    const float* __restrict__ bias,
    float* Cf, u16* Cb, int ldc,
    int Nreal, int K, int m0, int n0,
    int nsplit, float* C2, int ldc2, int act)
{
    const int tid = threadIdx.x;
    const int lane = tid & 63;
    const int w = tid >> 6;
    const int wr = w >> 1, wc = w & 1;

    float4v acc[4][4];
    #pragma unroll
    for (int i = 0; i < 4; ++i)
        #pragma unroll
        for (int j = 0; j < 4; ++j) acc[i][j] = (float4v){0.f, 0.f, 0.f, 0.f};

    {
        const int r0 = (w * 2 + 0) * 16 + (lane >> 2);
        const int r1 = (w * 2 + 1) * 16 + (lane >> 2);
        const int s0 = (lane & 3) ^ ((r0 >> 1) & 3);
        const int s1 = (lane & 3) ^ ((r1 >> 1) & 3);
        const u16* gA0 = A + (size_t)(m0 + r0) * lda + s0 * 8;
        const u16* gA1 = A + (size_t)(m0 + r1) * lda + s1 * 8;
        const u16* gB0 = B + (size_t)(n0 + r0) * ldb + s0 * 8;
        const u16* gB1 = B + (size_t)(n0 + r1) * ldb + s1 * 8;
        const int la0 = (w * 2 + 0) * 512;
        const int la1 = (w * 2 + 1) * 512;

        int ia[4], ib[4];
        #pragma unroll
        for (int mi = 0; mi < 4; ++mi) {
            const int r = wr * 64 + mi * 16 + (lane & 15);
            ia[mi] = r * 32 + (((lane >> 4) ^ ((r >> 1) & 3)) << 3);
        }
        #pragma unroll
        for (int nj = 0; nj < 4; ++nj) {
            const int r = wc * 64 + nj * 16 + (lane & 15);
            ib[nj] = r * 32 + (((lane >> 4) ^ ((r >> 1) & 3)) << 3);
        }

        const int nk = K >> 5;
        #pragma unroll
        for (int p = 0; p < 3; ++p) {
            const int ko = p * 32;
            gload16(gA0 + ko, AsB + p * 4096 + la0);
            gload16(gA1 + ko, AsB + p * 4096 + la1);
            gload16(gB0 + ko, BsB + p * 4096 + la0);
            gload16(gB1 + ko, BsB + p * 4096 + la1);
        }
        int cur = 0;
        for (int it = 0; it < nk; ++it) {
            const int rem = nk - 1 - it;
            if (rem >= 2)      asm volatile("s_waitcnt vmcnt(8)" ::: "memory");
            else if (rem == 1) asm volatile("s_waitcnt vmcnt(4)" ::: "memory");
            else               asm volatile("s_waitcnt vmcnt(0)" ::: "memory");
            __builtin_amdgcn_s_barrier();
            const u16* Asc = AsB + cur * 4096;
            const u16* Bsc = BsB + cur * 4096;
            short8v av[4], bv[4];
            #pragma unroll
            for (int mi = 0; mi < 4; ++mi) av[mi] = *(const short8v*)&Asc[ia[mi]];
            #pragma unroll
            for (int nj = 0; nj < 4; ++nj) bv[nj] = *(const short8v*)&Bsc[ib[nj]];
            __builtin_amdgcn_s_setprio(1);
            #pragma unroll
            for (int mi = 0; mi < 4; ++mi)
                #pragma unroll
                for (int nj = 0; nj < 4; ++nj)
                    acc[mi][nj] = __builtin_amdgcn_mfma_f32_16x16x32_bf16(
                        av[mi], bv[nj], acc[mi][nj], 0, 0, 0);
            __builtin_amdgcn_s_setprio(0);
            __builtin_amdgcn_s_barrier();
            if (it + 3 < nk) {
                const int ko = (it + 3) * 32;
                u16* Asw = AsB + cur * 4096;
                u16* Bsw = BsB + cur * 4096;
                gload16(gA0 + ko, Asw + la0);
                gload16(gA1 + ko, Asw + la1);
                gload16(gB0 + ko, Bsw + la0);
                gload16(gB1 + ko, Bsw + la1);
            }
            cur = (cur == 2) ? 0 : cur + 1;
        }
    }

    #pragma unroll
    for (int mi = 0; mi < 4; ++mi) {
        const int mbase = m0 + wr * 64 + mi * 16 + ((lane >> 4) << 2);
        #pragma unroll
        for (int nj = 0; nj < 4; ++nj) {
            const int n = n0 + wc * 64 + nj * 16 + (lane & 15);
            if (n >= Nreal) continue;
            const float bval = bias ? bias[n] : 0.f;
            #pragma unroll
            for (int r = 0; r < 4; ++r) {
                const int m = mbase + r;
                const float v = acc[mi][nj][r] + bval;
                if (n < nsplit) {
                    if (Cb) Cb[(size_t)m * ldc + n] = f2bf(v);
                    else    Cf[(size_t)m * ldc + n] = v;
                } else if (m < act) {
                    C2[(size_t)m * ldc2 + (n - nsplit)] = v;
                }
            }
        }
    }
}

// ---------------------------------------------------------------------------
// Attention job for one (active) sorted row b: e = relu(att1+att2).wfa + b;
// softmax(36); awe = (alpha @ objs)*sigmoid(gate) -> aweb bf16 (2048).
// ---------------------------------------------------------------------------
__device__ void attn_job(const MegaParams& P, int b, int t,
                         float (*wred)[40], float* es, float* alph)
{
    const int tid = threadIdx.x;
    if (t >= P.slen[b]) return;     // block-uniform; alphas pre-zeroed
    const int lane = tid & 63, w = tid >> 6;
    const float* hrow = P.Hcat + (size_t)b * 7168;
    const float4 h4 = ((const float4*)hrow)[tid];
    const float4 w4 = ((const float4*)P.wfa)[tid];
    const u16* a1base = P.att1b + (size_t)b * NOBJ * ATTD;

    float ep[NOBJ];
    #pragma unroll
    for (int n = 0; n < NOBJ; ++n) {
        ushort4 a4 = ((const ushort4*)(a1base + (size_t)n * ATTD))[tid];
        const float v0 = fmaxf(bu(a4.x) + h4.x, 0.f);
        const float v1 = fmaxf(bu(a4.y) + h4.y, 0.f);
        const float v2 = fmaxf(bu(a4.z) + h4.z, 0.f);
        const float v3 = fmaxf(bu(a4.w) + h4.w, 0.f);
        ep[n] = v0 * w4.x + v1 * w4.y + v2 * w4.z + v3 * w4.w;
    }
    #pragma unroll
    for (int n = 0; n < NOBJ; ++n) {
        float p = ep[n];
        #pragma unroll
        for (int off = 32; off > 0; off >>= 1) p += __shfl_down(p, off, 64);
        if (lane == 0) wred[w][n] = p;
    }
    __syncthreads();
    if (tid < NOBJ)
        es[tid] = wred[0][tid] + wred[1][tid] + wred[2][tid] + wred[3][tid] + P.bfa[0];
    __syncthreads();
    if (tid < 64) {
        float mv = (tid < NOBJ) ? es[tid] : -1e30f;
        #pragma unroll
        for (int off = 32; off > 0; off >>= 1) mv = fmaxf(mv, __shfl_xor(mv, off, 64));
        float e = (tid < NOBJ) ? expf(es[tid] - mv) : 0.f;
        float s = e;
        #pragma unroll
        for (int off = 32; off > 0; off >>= 1) s += __shfl_xor(s, off, 64);
        if (tid < NOBJ) alph[tid] = e / s;
    }
    __syncthreads();
    if (tid < NOBJ)
        P.out_alph[((size_t)b * TT + t) * NOBJ + tid] = alph[tid];

    float acc[8] = {0.f, 0.f, 0.f, 0.f, 0.f, 0.f, 0.f, 0.f};
    const u16* ob = P.objsb + (size_t)b * NOBJ * OBJD + tid * 8;
    #pragma unroll 4
    for (int n = 0; n < NOBJ; ++n) {
        const short8v ov = *(const short8v*)(ob + (size_t)n * OBJD);
        const float al = alph[n];
        #pragma unroll
        for (int j = 0; j < 8; ++j) acc[j] = fmaf(al, bu((u16)ov[j]), acc[j]);
    }
    const float* gp = hrow + 1024 + tid * 8;
    const float4 g0 = *(const float4*)gp;
    const float4 g1 = *(const float4*)(gp + 4);
    const float gt[8] = {sigf(g0.x), sigf(g0.y), sigf(g0.z), sigf(g0.w),
                         sigf(g1.x), sigf(g1.y), sigf(g1.z), sigf(g1.w)};
    short8v st;
    #pragma unroll
    for (int j = 0; j < 8; ++j) st[j] = (short)f2bf(acc[j] * gt[j]);
    *(short8v*)&P.aweb[(size_t)b * 2048 + tid * 8] = st;
}

// ---------------------------------------------------------------------------
// LSTM job for row b: gates = Gx[t,b] + sum_kz G2p[kz,b] + Hcat[b,3072:];
// update h, c, hb (active rows only).
// ---------------------------------------------------------------------------
__device__ void lstm_job(const MegaParams& P, int b, int t)
{
    if (t >= P.slen[b]) return;
    const int d4 = threadIdx.x;    // 256 float4 lanes = 1024 dims
    const float4* pw = (const float4*)(P.Hcat + (size_t)b * 7168 + 3072);
    const u16* gx = P.Gxb + ((size_t)(t * BB + b)) * 4096;

    float4 g[4];
    #pragma unroll
    for (int q = 0; q < 4; ++q) {
        const ushort4 xv = ((const ushort4*)(gx + q * 1024))[d4];
        float4 s;
        s.x = bu(xv.x); s.y = bu(xv.y); s.z = bu(xv.z); s.w = bu(xv.w);
        const float4 hv = pw[q * 256 + d4];
        s.x += hv.x; s.y += hv.y; s.z += hv.z; s.w += hv.w;
        #pragma unroll
        for (int p = 0; p < 4; ++p) {
            const float4 pv = ((const float4*)P.G2p)[(size_t)p * (BB * 1024) + b * 1024 + q * 256 + d4];
            s.x += pv.x; s.y += pv.y; s.z += pv.z; s.w += pv.w;
        }
        g[q] = s;
    }
    float4* hp = (float4*)(P.h + (size_t)b * 1024);
    float4* cp = (float4*)(P.c + (size_t)b * 1024);
    const float4 cold = cp[d4];
    float4 cn, hn;
    {
        const float si = sigf(g[0].x), sf = sigf(g[1].x), so = sigf(g[3].x);
        cn.x = sf * cold.x + si * tanhf(g[2].x); hn.x = so * tanhf(cn.x);
    }
    {
        const float si = sigf(g[0].y), sf = sigf(g[1].y), so = sigf(g[3].y);
        cn.y = sf * cold.y + si * tanhf(g[2].y); hn.y = so * tanhf(cn.y);
    }
    {
        const float si = sigf(g[0].z), sf = sigf(g[1].z), so = sigf(g[3].z);
        cn.z = sf * cold.z + si * tanhf(g[2].z); hn.z = so * tanhf(cn.z);
    }
    {
        const float si = sigf(g[0].w), sf = sigf(g[1].w), so = sigf(g[3].w);
        cn.w = sf * cold.w + si * tanhf(g[2].w); hn.w = so * tanhf(cn.w);
    }
    hp[d4] = hn;
    cp[d4] = cn;
    ushort4 s;
    s.x = f2bf(hn.x); s.y = f2bf(hn.y); s.z = f2bf(hn.z); s.w = f2bf(hn.w);
    ((ushort4*)(P.hb + (size_t)b * 1024))[d4] = s;
}

// ---------------------------------------------------------------------------
// Persistent megakernel: setup phases + full T-loop, grid = 256 x 256.
// ---------------------------------------------------------------------------
__global__ __launch_bounds__(256) void mega(MegaParams P)
{
    __shared__ u16 ldsA[3 * 4096];
    __shared__ u16 ldsB[3 * 4096];
    __shared__ float wred[4][40];
    __shared__ float es[40];
    __shared__ float alph[40];
    __shared__ int Ls[BB];
    __shared__ int SLs[BB];
    const int bid = blockIdx.x;
    const int tid = threadIdx.x;

    // ======== S1a: sort (block 0) + weight conversions + prezero + zero h,c
    if (bid == 0) {
        const int li = P.clen[tid];
        Ls[tid] = li;
        __syncthreads();
        int r = 0;
        for (int j = 0; j < BB; ++j) {
            const int lj = Ls[j];
            if (lj > li || (lj == li && j < tid)) r++;
        }
        P.sidx[r] = tid; P.slen[r] = li; SLs[r] = li;
        P.out_sind[r] = (float)tid; P.out_len[r] = (float)li;
        __syncthreads();
        if (tid < TT) {
            int cc = 0;
            for (int b2 = 0; b2 < BB; ++b2) cc += (SLs[b2] > tid);
            P.cnt[tid] = cc;
        }
    }
    // convWbig: rows of [Wda;Wfb;Whh;Wfc;pad] -> bf16 + bcat
    for (int n = bid; n < NBIGP; n += NGRID) {
        const float* src = nullptr;
        float bbv = 0.f;
        if (n < 1024)      { src = P.Wda + (size_t)n * 1024;          bbv = P.bda[n]; }
        else if (n < 3072) { src = P.Wfb + (size_t)(n - 1024) * 1024; bbv = P.bfb[n - 1024]; }
        else if (n < 7168) { src = P.Whh + (size_t)(n - 3072) * 1024; }
        else if (n < NBIG) { src = P.Wfc + (size_t)(n - 7168) * 1024; bbv = P.bfc[n - 7168]; }
        ushort4 s4;
        if (src) {
            float4 v = ((const float4*)src)[tid];
            s4.x = f2bf(v.x); s4.y = f2bf(v.y); s4.z = f2bf(v.z); s4.w = f2bf(v.w);
        } else { s4.x = s4.y = s4.z = s4.w = 0; }
        ((ushort4*)(P.Wbigb + (size_t)n * 1024))[tid] = s4;
        if (tid == 0) P.bcat[n] = bbv;
    }
    // convWih + bsum
    for (int n = bid; n < 4096; n += NGRID) {
        const float* src = P.Wih + (size_t)n * 3072;
        u16* dst = P.Wihb + (size_t)n * 3072;
        #pragma unroll
        for (int j = 0; j < 3; ++j) {
            float4 v = ((const float4*)src)[tid + 256 * j];
            ushort4 s4;
            s4.x = f2bf(v.x); s4.y = f2bf(v.y); s4.z = f2bf(v.z); s4.w = f2bf(v.w);
            ((ushort4*)dst)[tid + 256 * j] = s4;
        }
        if (tid == 0) P.bsum[n] = P.bih[n] + P.bhh[n];
    }
    // convWea
    for (int n = bid; n < 1024; n += NGRID) {
        const float* src = P.Wea + (size_t)n * OBJD;
        u16* dst = P.Weab + (size_t)n * OBJD;
        #pragma unroll
        for (int j = 0; j < 2; ++j) {
            float4 v = ((const float4*)src)[tid + 256 * j];
            ushort4 s4;
            s4.x = f2bf(v.x); s4.y = f2bf(v.y); s4.z = f2bf(v.z); s4.w = f2bf(v.w);
            ((ushort4*)dst)[tid + 256 * j] = s4;
        }
    }
    // zero h, c (block bid owns row bid)
    {
        const float4 z4 = make_float4(0.f, 0.f, 0.f, 0.f);
        ((float4*)(P.h + (size_t)bid * 1024))[tid] = z4;
        ((float4*)(P.c + (size_t)bid * 1024))[tid] = z4;
        // prezero predictions (51.2M f32) + alphas (184320 f32)
        float4* o4 = (float4*)P.outP;
        for (size_t i = (size_t)bid * 256 + tid; i < 12800000u; i += NGRID * 256) o4[i] = z4;
        float4* a4 = (float4*)P.out_alph;
        for (int i = bid * 256 + tid; i < 46080; i += NGRID * 256) a4[i] = z4;
    }
    grid_bar(P.bar);

    // ======== S1b: gather objs (sorted, bf16), embeddings, caps, Hcat(0)
    for (int row = bid; row < BB * NOBJ; row += NGRID) {
        const int b = row / NOBJ, n = row - b * NOBJ;
        const float* src = P.objs + ((size_t)P.sidx[b] * NOBJ + n) * OBJD;
        u16* dst = P.objsb + (size_t)row * OBJD;
        #pragma unroll
        for (int j = 0; j < 2; ++j) {
            float4 v = ((const float4*)src)[tid + 256 * j];
            ushort4 s4;
            s4.x = f2bf(v.x); s4.y = f2bf(v.y); s4.z = f2bf(v.z); s4.w = f2bf(v.w);
            ((ushort4*)dst)[tid + 256 * j] = s4;
        }
    }
    for (int blk = bid; blk < TT * BB; blk += NGRID) {
        const int t = blk >> 8, b = blk & 255;
        const int sb = P.sidx[b];
        const float* src = (t == 0) ? (P.enc + (size_t)sb * DECD)
                                    : (P.emb + (size_t)P.caps[sb * TT + (t - 1)] * DECD);
        float4 v = ((const float4*)src)[tid];
        ushort4 s4;
        s4.x = f2bf(v.x); s4.y = f2bf(v.y); s4.z = f2bf(v.z); s4.w = f2bf(v.w);
        ((ushort4*)(P.Xb + (size_t)blk * DECD))[tid] = s4;
    }
    if (bid == 1) {
        for (int i = tid; i < BB * TT; i += 256) {
            const int p = i / TT, t = i % TT;
            P.out_caps[i] = (float)P.caps[P.sidx[p] * TT + t];
        }
    }
    // Hcat(0) = bcat broadcast (h0 = 0)
    {
        const float4* src = (const float4*)P.bcat;
        float4* dst = (float4*)(P.Hcat + (size_t)bid * 7168);
        for (int i = tid; i < 1792; i += 256) dst[i] = src[i];
    }
    grid_bar(P.bar);

    // ======== S2: att1 GEMM (576 jobs) + Gx GEMM (1280 jobs)
    for (int j = bid; j < 576 + 1280; j += NGRID) {
        if (j < 576) {
            const int n = j / 72, m = j % 72;    // 8 n-tiles x 72 m-tiles
            gemm_job(ldsA, ldsB, P.objsb, OBJD, P.Weab, OBJD, P.bea,
                     nullptr, P.att1b, ATTD, ATTD, OBJD, m * 128, n * 128,
                     1 << 30, nullptr, 0, 1 << 30);
        } else {
            const int j2 = j - 576;
            const int n = j2 / 40, m = j2 % 40;  // 32 n-tiles x 40 m-tiles
            gemm_job(ldsA, ldsB, P.Xb, DECD, P.Wihb, 3072, P.bsum,
                     nullptr, P.Gxb, 4096, 4096, DECD, m * 128, n * 128,
                     1 << 30, nullptr, 0, 1 << 30);
        }
    }
    grid_bar(P.bar);

    // ======== T-loop
    for (int t = 0; t < TT; ++t) {
        const int act = P.cnt[t];
        const int mt = (act > 128) ? 2 : 1;

        // attention (one block per sorted row)
        attn_job(P, bid, t, wred, es, alph);
        grid_bar(P.bar);

        // G2 partials = awe @ Wih[:,1024:3072]^T  (kz-split x4, K=512 each)
        for (int j = bid; j < mt * 128; j += NGRID) {
            const int kz = j & 3, q = j >> 2;
            const int n = q & 31, m = q >> 5;
            gemm_job(ldsA, ldsB,
                     P.aweb + kz * 512, 2048,
                     P.Wihb + 1024 + kz * 512, 3072,
                     nullptr, P.G2p + (size_t)kz * (BB * 4096), nullptr, 4096,
                     4096, 512, m * 128, n * 128, 1 << 30, nullptr, 0, 1 << 30);
        }
        grid_bar(P.bar);

        // LSTM update (one block per row)
        lstm_job(P, bid, t);
        grid_bar(P.bar);

        // fused [Hcat(t+1) | preds(t)] = h @ Wbig^T + bcat
        for (int j = bid; j < mt * 135; j += NGRID) {
            int n, m;
            if (mt == 2) { n = j >> 1; m = j & 1; } else { n = j; m = 0; }
            gemm_job(ldsA, ldsB, P.hb, DECD, P.Wbigb, DECD, P.bcat,
                     P.Hcat, nullptr, 7168, NBIG, DECD, m * 128, n * 128,
                     NSPLIT, P.outP + (size_t)t * VOCAB, TT * VOCAB, act);
        }
        grid_bar(P.bar);
    }
}

// ---------------------------------------------------------------------------
extern "C" void kernel_launch(void* const* d_in, const int* in_sizes, int n_in,
                              void* d_out, int out_size, void* d_ws, size_t ws_size,
                              hipStream_t stream)
{
    MegaParams P;
    P.enc  = (const float*)d_in[0];
    P.objs = (const float*)d_in[1];
    P.caps = (const int*)d_in[2];
    P.clen = (const int*)d_in[3];
    P.emb  = (const float*)d_in[4];
    P.Wea  = (const float*)d_in[5];
    P.bea  = (const float*)d_in[6];
    P.Wda  = (const float*)d_in[7];
    P.bda  = (const float*)d_in[8];
    P.wfa  = (const float*)d_in[9];
    P.bfa  = (const float*)d_in[10];
    P.Wfb  = (const float*)d_in[11];
    P.bfb  = (const float*)d_in[12];
    P.Wih  = (const float*)d_in[13];
    P.Whh  = (const float*)d_in[14];
    P.bih  = (const float*)d_in[15];
    P.bhh  = (const float*)d_in[16];
    P.Wfc  = (const float*)d_in[17];
    P.bfc  = (const float*)d_in[18];

    P.outP     = (float*)d_out;
    P.out_caps = P.outP + (size_t)BB * TT * VOCAB;
    P.out_len  = P.out_caps + BB * TT;
    P.out_alph = P.out_len + BB;
    P.out_sind = P.out_alph + (size_t)BB * TT * NOBJ;

    char* wp = (char*)d_ws;
    auto alloc = [&](size_t bytes) -> void* {
        void* r = (void*)wp;
        wp += (bytes + 255) & ~(size_t)255;
        return r;
    };
    P.bar   = (int*)alloc(256);
    P.sidx  = (int*)alloc(BB * 4);
    P.slen  = (int*)alloc(BB * 4);
    P.cnt   = (int*)alloc(32 * 4);
    P.objsb = (u16*)alloc((size_t)BB * NOBJ * OBJD * 2);
    P.Wbigb = (u16*)alloc((size_t)NBIGP * 1024 * 2);
    P.bcat  = (float*)alloc(NBIGP * 4);
    P.Wihb  = (u16*)alloc((size_t)4096 * 3072 * 2);
    P.bsum  = (float*)alloc(4096 * 4);
    P.Weab  = (u16*)alloc((size_t)1024 * OBJD * 2);
    P.att1b = (u16*)alloc((size_t)BB * NOBJ * ATTD * 2);
    P.Xb    = (u16*)alloc((size_t)TT * BB * DECD * 2);
    P.Gxb   = (u16*)alloc((size_t)TT * BB * 4096 * 2);
    P.Hcat  = (float*)alloc((size_t)BB * 7168 * 4);
    P.aweb  = (u16*)alloc((size_t)BB * 2048 * 2);
    P.G2p   = (float*)alloc((size_t)4 * BB * 4096 * 4);
    P.h     = (float*)alloc((size_t)BB * DECD * 4);
    P.c     = (float*)alloc((size_t)BB * DECD * 4);
    P.hb    = (u16*)alloc((size_t)BB * DECD * 2);
    (void)ws_size; (void)in_sizes; (void)n_in; (void)out_size;

    hipMemsetAsync(P.bar, 0, 256, stream);
    mega<<<NGRID, 256, 0, stream>>>(P);
}